// Round 1
// baseline (125.410 us; speedup 1.0000x reference)
//
#include <hip/hip_runtime.h>

#ifndef __has_builtin
#define __has_builtin(x) 0
#endif

#if __has_builtin(__builtin_amdgcn_exp2f)
__device__ __forceinline__ float fexp2(float x) { return __builtin_amdgcn_exp2f(x); }
#else
__device__ __forceinline__ float fexp2(float x) { return exp2f(x); }
#endif
#if __has_builtin(__builtin_amdgcn_logf)
__device__ __forceinline__ float flog2(float x) { return __builtin_amdgcn_logf(x); }
#else
__device__ __forceinline__ float flog2(float x) { return log2f(x); }
#endif

#define L2E 1.4426950408889634f   // log2(e)
#define LN2 0.6931471805599453f   // 1/log2(e)
#define BIGL (1.0e10f * L2E)      // BIG in log2-scaled domain

// One wave (64 threads) per batch element. Lane t owns DP rows 4t+1..4t+4
// (1-indexed). R' = log2(e) * R so softmin uses native exp2/log2 only.
__global__ __launch_bounds__(64) void softdtw_kernel(
    const float* __restrict__ x, const float* __restrict__ y,
    float* __restrict__ out)
{
  const int b = blockIdx.x;
  const int t = threadIdx.x;  // 0..63

  // z rows bucketed by (row & 3): lane reads at stride 9 words -> conflict-free
  __shared__ float zbuf[4][64][9];

  const float* xb = x + (size_t)b * 256 * 8;
  const float* yb = y + (size_t)b * 256 * 8;

  float xe[4][9];   // [x0..x7, 1.0]
  float x2L[4];     // log2(e) * ||x||^2

  // ---- stage y -> z (LDS) and x -> registers ----
  #pragma unroll
  for (int r = 0; r < 4; ++r) {
    const int row = 4 * t + r;
    float4 a = *(const float4*)(yb + row * 8);
    float4 c = *(const float4*)(yb + row * 8 + 4);
    float y2 = a.x*a.x + a.y*a.y + a.z*a.z + a.w*a.w
             + c.x*c.x + c.y*c.y + c.z*c.z + c.w*c.w;
    float* zr = &zbuf[r][t][0];  // row&3 == r, row>>2 == t
    zr[0] = -2.0f * L2E * a.x; zr[1] = -2.0f * L2E * a.y;
    zr[2] = -2.0f * L2E * a.z; zr[3] = -2.0f * L2E * a.w;
    zr[4] = -2.0f * L2E * c.x; zr[5] = -2.0f * L2E * c.y;
    zr[6] = -2.0f * L2E * c.z; zr[7] = -2.0f * L2E * c.w;
    zr[8] = L2E * y2;

    float4 xa = *(const float4*)(xb + row * 8);
    float4 xc = *(const float4*)(xb + row * 8 + 4);
    xe[r][0] = xa.x; xe[r][1] = xa.y; xe[r][2] = xa.z; xe[r][3] = xa.w;
    xe[r][4] = xc.x; xe[r][5] = xc.y; xe[r][6] = xc.z; xe[r][7] = xc.w;
    xe[r][8] = 1.0f;
    x2L[r] = L2E * (xa.x*xa.x + xa.y*xa.y + xa.z*xa.z + xa.w*xa.w
                  + xc.x*xc.x + xc.y*xc.y + xc.z*xc.z + xc.w*xc.w);
  }
  __syncthreads();

  // sliding z rows (register-resident, rotated by 4-step unroll)
  float zA[9], zB[9], zC[9], zD[9];
  #pragma unroll
  for (int w = 0; w < 9; ++w) { zA[w] = 0.f; zB[w] = 0.f; zC[w] = 0.f; zD[w] = 0.f; }

  float RA[4] = {BIGL, BIGL, BIGL, BIGL};  // diag k-2 (then rotates)
  float RB[4] = {BIGL, BIGL, BIGL, BIGL};  // diag k-1 (then rotates)

  int u = -4 * t;  // u = k - 2 - 4t  (z row index for this lane's top row)

  // one cell: softmin in log2 domain + fused distance
  auto ROW = [&](int r, float a, float bb, float c, const float (&zr)[9]) -> float {
    float acc = x2L[r];
    #pragma unroll
    for (int d = 0; d < 9; ++d) acc = fmaf(xe[r][d], zr[d], acc);
    float m = fminf(fminf(a, bb), c);
    float e = fexp2(m - a) + fexp2(m - bb) + fexp2(m - c);
    float sm = m - flog2(e);
    float val = acc + sm;
    return ((unsigned)(u - r) < 256u) ? val : BIGL;
  };

  // one anti-diagonal: load new z row into zw, rows use (zw,zx,zy,zz),
  // read Rm1 (k-1) / Rm2 (k-2), write new diag into Rm2.
  auto STEP = [&](float (&zw)[9], const float (&zx)[9], const float (&zy)[9],
                  const float (&zz)[9], float (&Rm2)[4], float (&Rm1)[4],
                  int p, int k) {
    int uc = u < 0 ? 0 : (u > 255 ? 255 : u);
    const float* zptr = &zbuf[p][uc >> 2][0];
    #pragma unroll
    for (int w = 0; w < 9; ++w) zw[w] = zptr[w];

    float up_in = __shfl_up(Rm1[3], 1);  // R[4t, j]   (prev lane last row)
    float dg_in = __shfl_up(Rm2[3], 1);  // R[4t, j-1]
    float bval = (k == 2) ? 0.0f : BIGL; // R[0, k-2]: 0 only at k==2
    if (t == 0) { up_in = BIGL; dg_in = bval; }

    float nv0 = ROW(0, dg_in,  up_in,  Rm1[0], zw);
    float nv1 = ROW(1, Rm2[0], Rm1[0], Rm1[1], zx);
    float nv2 = ROW(2, Rm2[1], Rm1[1], Rm1[2], zy);
    float nv3 = ROW(3, Rm2[2], Rm1[2], Rm1[3], zz);
    Rm2[0] = nv0; Rm2[1] = nv1; Rm2[2] = nv2; Rm2[3] = nv3;
    u += 1;
  };

  // k = 2 .. 512 (511 diagonals) = 127*4 + 3
  int k = 2;
  for (int mi = 0; mi < 127; ++mi) {
    STEP(zD, zA, zB, zC, RA, RB, 0, k);
    STEP(zC, zD, zA, zB, RB, RA, 1, k + 1);
    STEP(zB, zC, zD, zA, RA, RB, 2, k + 2);
    STEP(zA, zB, zC, zD, RB, RA, 3, k + 3);
    k += 4;
  }
  STEP(zD, zA, zB, zC, RA, RB, 0, k);      // k = 510
  STEP(zC, zD, zA, zB, RB, RA, 1, k + 1);  // k = 511
  STEP(zB, zC, zD, zA, RA, RB, 2, k + 2);  // k = 512 -> result in RA

  if (t == 63) out[b] = RA[3] * LN2;  // R[256,256] = R' * ln2
}

extern "C" void kernel_launch(void* const* d_in, const int* in_sizes, int n_in,
                              void* d_out, int out_size, void* d_ws, size_t ws_size,
                              hipStream_t stream) {
  const float* x = (const float*)d_in[0];
  const float* y = (const float*)d_in[1];
  float* out = (float*)d_out;
  const int B = in_sizes[0] / (256 * 8);
  softdtw_kernel<<<dim3(B), dim3(64), 0, stream>>>(x, y, out);
}

// Round 2
// 123.294 us; speedup vs baseline: 1.0172x; 1.0172x over previous
//
#include <hip/hip_runtime.h>

#ifndef __has_builtin
#define __has_builtin(x) 0
#endif

#if __has_builtin(__builtin_amdgcn_exp2f)
__device__ __forceinline__ float fexp2(float x) { return __builtin_amdgcn_exp2f(x); }
#else
__device__ __forceinline__ float fexp2(float x) { return exp2f(x); }
#endif
#if __has_builtin(__builtin_amdgcn_logf)
__device__ __forceinline__ float flog2(float x) { return __builtin_amdgcn_logf(x); }
#else
__device__ __forceinline__ float flog2(float x) { return log2f(x); }
#endif

#define L2E 1.4426950408889634f   // log2(e)
#define LN2 0.6931471805599453f
#define BIGL (1.0e10f * L2E)      // BIG in log2-scaled domain

// lane i <- lane i-1 via DPP wave_shr:1 (VALU op, no LDS/lgkmcnt)
__device__ __forceinline__ float shup1(float v) {
  int r = __builtin_amdgcn_update_dpp(0, __builtin_bit_cast(int, v),
                                      0x138 /*wave_shr:1*/, 0xF, 0xF, false);
  return __builtin_bit_cast(float, r);
}

// One wave per batch element; lane t owns DP rows 4t+1..4t+4 (1-indexed).
// R' = log2(e)*R so softmin uses native v_exp/v_log only.
__global__ __launch_bounds__(64) void softdtw_kernel(
    const float* __restrict__ x, const float* __restrict__ y,
    float* __restrict__ out)
{
  const int b = blockIdx.x;
  const int t = threadIdx.x;  // 0..63

  // y rows bucketed by (row & 3), pitch 10 words (8B-aligned rows)
  __shared__ float zbuf[4][64][10];

  const float* xb = x + (size_t)b * 256 * 8;
  const float* yb = y + (size_t)b * 256 * 8;

  float xe[4][8];
  float x2L[4];

  #pragma unroll
  for (int r = 0; r < 4; ++r) {
    const int row = 4 * t + r;
    float4 a = *(const float4*)(yb + row * 8);
    float4 c = *(const float4*)(yb + row * 8 + 4);
    float y2 = a.x*a.x + a.y*a.y + a.z*a.z + a.w*a.w
             + c.x*c.x + c.y*c.y + c.z*c.z + c.w*c.w;
    float* zw_ = &zbuf[r][t][0];
    zw_[0] = -2.0f * L2E * a.x; zw_[1] = -2.0f * L2E * a.y;
    zw_[2] = -2.0f * L2E * a.z; zw_[3] = -2.0f * L2E * a.w;
    zw_[4] = -2.0f * L2E * c.x; zw_[5] = -2.0f * L2E * c.y;
    zw_[6] = -2.0f * L2E * c.z; zw_[7] = -2.0f * L2E * c.w;
    zw_[8] = L2E * y2;

    float4 xa = *(const float4*)(xb + row * 8);
    float4 xc = *(const float4*)(xb + row * 8 + 4);
    xe[r][0] = xa.x; xe[r][1] = xa.y; xe[r][2] = xa.z; xe[r][3] = xa.w;
    xe[r][4] = xc.x; xe[r][5] = xc.y; xe[r][6] = xc.z; xe[r][7] = xc.w;
    x2L[r] = L2E * (xa.x*xa.x + xa.y*xa.y + xa.z*xa.z + xa.w*xa.w
                  + xc.x*xc.x + xc.y*xc.y + xc.z*xc.z + xc.w*xc.w);
  }
  __syncthreads();

  float zn[8][9];                 // register ring of z rows, slot = step & 7
  #pragma unroll
  for (int s_ = 0; s_ < 8; ++s_)
    #pragma unroll
    for (int w_ = 0; w_ < 9; ++w_) zn[s_][w_] = 0.f;

  float RA[4] = {BIGL, BIGL, BIGL, BIGL};
  float RB[4] = {BIGL, BIGL, BIGL, BIGL};

  int u = -4 * t;   // z-row (j0) index of this lane's ROW(0) at current step

  // prologue: rows for steps 0..3 into slots 0..3 (bucket = step & 3)
  #define PROLOAD(slot, p) do {                                          \
    int v_ = u + (slot); int vc_ = v_ < 0 ? 0 : (v_ > 255 ? 255 : v_);   \
    const float* zp_ = &zbuf[p][vc_ >> 2][0];                            \
    _Pragma("unroll") for (int w_ = 0; w_ < 9; ++w_) zn[slot][w_] = zp_[w_]; \
  } while (0)
  PROLOAD(0, 0); PROLOAD(1, 1); PROLOAD(2, 2); PROLOAD(3, 3);

  // one cell, log2-domain softmin + fused distance (r must be a literal)
  #define ROW(r, a_, b_, c_, zrow) ({                                    \
    float acc_ = x2L[r] + (zrow)[8];                                     \
    _Pragma("unroll") for (int w_ = 0; w_ < 8; ++w_)                     \
      acc_ = fmaf(xe[r][w_], (zrow)[w_], acc_);                          \
    float mn_ = fminf(fminf((a_), (b_)), (c_));                          \
    float e_ = fexp2(mn_ - (a_)) + fexp2(mn_ - (b_)) + fexp2(mn_ - (c_));\
    float val_ = acc_ + (mn_ - flog2(e_));                               \
    ((unsigned)(u - (r)) < 256u) ? val_ : BIGL; })

  // one diagonal at unroll position q (q = step & 7, compile-time):
  // prefetch z row for step+4, then compute 4 cells. R2 = diag s-2 (written).
  #define STEPQ(q, R2, R1) do {                                          \
    { int v_ = u + 4; int vc_ = v_ < 0 ? 0 : (v_ > 255 ? 255 : v_);      \
      const float* zp_ = &zbuf[(q) & 3][vc_ >> 2][0];                    \
      _Pragma("unroll") for (int w_ = 0; w_ < 9; ++w_)                   \
        zn[((q) + 4) & 7][w_] = zp_[w_]; }                               \
    float up_ = shup1(R1[3]);                                            \
    float dg_ = shup1(R2[3]);                                            \
    if (t == 0) { up_ = BIGL; dg_ = (u == 0) ? 0.0f : BIGL; }            \
    float n0_ = ROW(0, dg_,   up_,   R1[0], zn[(q) & 7]);                \
    float n1_ = ROW(1, R2[0], R1[0], R1[1], zn[((q) + 7) & 7]);          \
    float n2_ = ROW(2, R2[1], R1[1], R1[2], zn[((q) + 6) & 7]);          \
    float n3_ = ROW(3, R2[2], R1[2], R1[3], zn[((q) + 5) & 7]);          \
    R2[0] = n0_; R2[1] = n1_; R2[2] = n2_; R2[3] = n3_;                  \
    u += 1;                                                              \
  } while (0)

  // 511 diagonals = 63*8 + 7; even step writes RA, odd writes RB
  for (int m8 = 0; m8 < 63; ++m8) {
    STEPQ(0, RA, RB); STEPQ(1, RB, RA); STEPQ(2, RA, RB); STEPQ(3, RB, RA);
    STEPQ(4, RA, RB); STEPQ(5, RB, RA); STEPQ(6, RA, RB); STEPQ(7, RB, RA);
  }
  STEPQ(0, RA, RB); STEPQ(1, RB, RA); STEPQ(2, RA, RB); STEPQ(3, RB, RA);
  STEPQ(4, RA, RB); STEPQ(5, RB, RA); STEPQ(6, RA, RB);  // step 510 -> RA

  if (t == 63) out[b] = RA[3] * LN2;
}

extern "C" void kernel_launch(void* const* d_in, const int* in_sizes, int n_in,
                              void* d_out, int out_size, void* d_ws, size_t ws_size,
                              hipStream_t stream) {
  const float* x = (const float*)d_in[0];
  const float* y = (const float*)d_in[1];
  float* out = (float*)d_out;
  const int B = in_sizes[0] / (256 * 8);
  softdtw_kernel<<<dim3(B), dim3(64), 0, stream>>>(x, y, out);
}

// Round 3
// 119.490 us; speedup vs baseline: 1.0495x; 1.0318x over previous
//
#include <hip/hip_runtime.h>

#ifndef __has_builtin
#define __has_builtin(x) 0
#endif

#if __has_builtin(__builtin_amdgcn_exp2f)
__device__ __forceinline__ float fexp2(float x) { return __builtin_amdgcn_exp2f(x); }
#else
__device__ __forceinline__ float fexp2(float x) { return exp2f(x); }
#endif
#if __has_builtin(__builtin_amdgcn_logf)
__device__ __forceinline__ float flog2(float x) { return __builtin_amdgcn_logf(x); }
#else
__device__ __forceinline__ float flog2(float x) { return log2f(x); }
#endif

#define L2E 1.4426950408889634f   // log2(e)
#define LN2 0.6931471805599453f
#define BIGL (1.0e10f * L2E)      // BIG in log2-scaled domain

// lane i <- lane i-1 via DPP wave_shr:1 (VALU op, no LDS/lgkmcnt)
__device__ __forceinline__ float shup1(float v) {
  int r = __builtin_amdgcn_update_dpp(0, __builtin_bit_cast(int, v),
                                      0x138 /*wave_shr:1*/, 0xF, 0xF, false);
  return __builtin_bit_cast(float, r);
}

// One wave per batch element; lane t owns DP rows 4t+1..4t+4 (1-indexed).
// R' = log2(e)*R so softmin uses native v_exp/v_log only.
__global__ __launch_bounds__(64) void softdtw_kernel(
    const float* __restrict__ x, const float* __restrict__ y,
    float* __restrict__ out)
{
  const int b = blockIdx.x;
  const int t = threadIdx.x;  // 0..63

  // y rows bucketed by (row & 3), pitch 9 words: lane stride 9 -> conflict-free
  __shared__ float zbuf[4][64][9];

  const float* xb = x + (size_t)b * 256 * 8;
  const float* yb = y + (size_t)b * 256 * 8;

  float xe[4][8];
  float x2L[4];

  #pragma unroll
  for (int r = 0; r < 4; ++r) {
    const int row = 4 * t + r;
    float4 a = *(const float4*)(yb + row * 8);
    float4 c = *(const float4*)(yb + row * 8 + 4);
    float y2 = a.x*a.x + a.y*a.y + a.z*a.z + a.w*a.w
             + c.x*c.x + c.y*c.y + c.z*c.z + c.w*c.w;
    float* zw_ = &zbuf[r][t][0];
    zw_[0] = -2.0f * L2E * a.x; zw_[1] = -2.0f * L2E * a.y;
    zw_[2] = -2.0f * L2E * a.z; zw_[3] = -2.0f * L2E * a.w;
    zw_[4] = -2.0f * L2E * c.x; zw_[5] = -2.0f * L2E * c.y;
    zw_[6] = -2.0f * L2E * c.z; zw_[7] = -2.0f * L2E * c.w;
    zw_[8] = L2E * y2;

    float4 xa = *(const float4*)(xb + row * 8);
    float4 xc = *(const float4*)(xb + row * 8 + 4);
    xe[r][0] = xa.x; xe[r][1] = xa.y; xe[r][2] = xa.z; xe[r][3] = xa.w;
    xe[r][4] = xc.x; xe[r][5] = xc.y; xe[r][6] = xc.z; xe[r][7] = xc.w;
    x2L[r] = L2E * (xa.x*xa.x + xa.y*xa.y + xa.z*xa.z + xa.w*xa.w
                  + xc.x*xc.x + xc.y*xc.y + xc.z*xc.z + xc.w*xc.w);
  }
  __syncthreads();

  // ring of z rows: slot (step & 7) holds the row consumed by ROW(0) at that
  // step (row index u_step). Loaded at the TOP of step-1, pinned by a
  // sched_barrier so the scheduler cannot sink the ds_reads to their use.
  float zn[8][9];
  #pragma unroll
  for (int s_ = 0; s_ < 8; ++s_)
    #pragma unroll
    for (int w_ = 0; w_ < 9; ++w_) zn[s_][w_] = 0.f;

  float RA[4] = {BIGL, BIGL, BIGL, BIGL};
  float RB[4] = {BIGL, BIGL, BIGL, BIGL};

  int u = -4 * t;   // z-row index of this lane's ROW(0) at the current step

  // prologue: slots for steps 0,-1,-2,-3 (rows u, u-1, u-2, u-3)
  #define PROLOAD(slot, delta, p) do {                                   \
    int v_ = u - (delta); int vc_ = v_ < 0 ? 0 : (v_ > 255 ? 255 : v_);  \
    const float* zp_ = &zbuf[p][vc_ >> 2][0];                            \
    _Pragma("unroll") for (int w_ = 0; w_ < 9; ++w_) zn[slot][w_] = zp_[w_]; \
  } while (0)
  PROLOAD(0, 0, 0); PROLOAD(7, 1, 3); PROLOAD(6, 2, 2); PROLOAD(5, 3, 1);

  // one cell, log2-domain softmin + fused distance (r must be a literal)
  #define ROW(r, a_, b_, c_, zrow) ({                                    \
    float acc_ = x2L[r] + (zrow)[8];                                     \
    _Pragma("unroll") for (int w_ = 0; w_ < 8; ++w_)                     \
      acc_ = fmaf(xe[r][w_], (zrow)[w_], acc_);                          \
    float mn_ = fminf(fminf((a_), (b_)), (c_));                          \
    float e_ = fexp2(mn_ - (a_)) + fexp2(mn_ - (b_)) + fexp2(mn_ - (c_));\
    float val_ = acc_ + (mn_ - flog2(e_));                               \
    ((unsigned)(u - (r)) < 256u) ? val_ : BIGL; })

  // one diagonal at unroll position q (= step & 7, compile-time):
  // 1) issue 9 ds_read_b32 for next step's row into slot (q+1)&7
  // 2) sched_barrier(0) — pins the loads here (R2 lesson: without the
  //    fence the scheduler sinks them to use and exposes LDS latency)
  // 3) DPP boundary pull + 4 cells from slots q, q-1, q-2, q-3
  #define STEPQ(q, R2, R1) do {                                          \
    { int v_ = u + 1; int vc_ = v_ < 0 ? 0 : (v_ > 255 ? 255 : v_);      \
      const float* zp_ = &zbuf[((q) + 1) & 3][vc_ >> 2][0];              \
      _Pragma("unroll") for (int w_ = 0; w_ < 9; ++w_)                   \
        zn[((q) + 1) & 7][w_] = zp_[w_]; }                               \
    __builtin_amdgcn_sched_barrier(0);                                   \
    float up_ = shup1(R1[3]);                                            \
    float dg_ = shup1(R2[3]);                                            \
    if (t == 0) { up_ = BIGL; dg_ = (u == 0) ? 0.0f : BIGL; }            \
    float n0_ = ROW(0, dg_,   up_,   R1[0], zn[(q) & 7]);                \
    float n1_ = ROW(1, R2[0], R1[0], R1[1], zn[((q) + 7) & 7]);          \
    float n2_ = ROW(2, R2[1], R1[1], R1[2], zn[((q) + 6) & 7]);          \
    float n3_ = ROW(3, R2[2], R1[2], R1[3], zn[((q) + 5) & 7]);          \
    R2[0] = n0_; R2[1] = n1_; R2[2] = n2_; R2[3] = n3_;                  \
    u += 1;                                                              \
  } while (0)

  // 511 diagonals = 63*8 + 7; even step writes RA, odd writes RB
  for (int m8 = 0; m8 < 63; ++m8) {
    STEPQ(0, RA, RB); STEPQ(1, RB, RA); STEPQ(2, RA, RB); STEPQ(3, RB, RA);
    STEPQ(4, RA, RB); STEPQ(5, RB, RA); STEPQ(6, RA, RB); STEPQ(7, RB, RA);
  }
  STEPQ(0, RA, RB); STEPQ(1, RB, RA); STEPQ(2, RA, RB); STEPQ(3, RB, RA);
  STEPQ(4, RA, RB); STEPQ(5, RB, RA); STEPQ(6, RA, RB);  // step 510 -> RA

  if (t == 63) out[b] = RA[3] * LN2;
}

extern "C" void kernel_launch(void* const* d_in, const int* in_sizes, int n_in,
                              void* d_out, int out_size, void* d_ws, size_t ws_size,
                              hipStream_t stream) {
  const float* x = (const float*)d_in[0];
  const float* y = (const float*)d_in[1];
  float* out = (float*)d_out;
  const int B = in_sizes[0] / (256 * 8);
  softdtw_kernel<<<dim3(B), dim3(64), 0, stream>>>(x, y, out);
}

// Round 7
// 67.742 us; speedup vs baseline: 1.8513x; 1.7639x over previous
//
#include <hip/hip_runtime.h>

#ifndef __has_builtin
#define __has_builtin(x) 0
#endif

#if __has_builtin(__builtin_amdgcn_logf)
__device__ __forceinline__ float flog2(float x) { return __builtin_amdgcn_logf(x); }
#else
__device__ __forceinline__ float flog2(float x) { return log2f(x); }
#endif

#define L2E 1.4426950408889634f   // log2(e)
#define LN2 0.6931471805599453
#define BIGL (1.0e10f * L2E)

template <int CTRL, int RM, int BM>
__device__ __forceinline__ float dpp_f(float v, float old) {
  int r = __builtin_amdgcn_update_dpp(__builtin_bit_cast(int, old),
                                      __builtin_bit_cast(int, v),
                                      CTRL, RM, BM, false);
  return __builtin_bit_cast(float, r);
}

// lane i <- lane i-1; lane 0 <- 0. fp64 via DPP on both halves.
__device__ __forceinline__ double shup1z_d(double v) {
  int lo = __double2loint(v), hi = __double2hiint(v);
  int lo2 = __builtin_amdgcn_update_dpp(0, lo, 0x138, 0xF, 0xF, false);
  int hi2 = __builtin_amdgcn_update_dpp(0, hi, 0x138, 0xF, 0xF, false);
  return __hiloint2double(hi2, lo2);
}

// wave max -> lane 63 (nonnegative floats)
__device__ __forceinline__ float wave_max63(float m) {
  m = fmaxf(m, dpp_f<0x111, 0xF, 0xF>(m, m));  // row_shr:1
  m = fmaxf(m, dpp_f<0x112, 0xF, 0xF>(m, m));  // row_shr:2
  m = fmaxf(m, dpp_f<0x114, 0xF, 0xF>(m, m));  // row_shr:4
  m = fmaxf(m, dpp_f<0x118, 0xF, 0xF>(m, m));  // row_shr:8
  m = fmaxf(m, dpp_f<0x142, 0xA, 0xF>(m, m));  // row_bcast15 -> rows 1,3
  m = fmaxf(m, dpp_f<0x143, 0xC, 0xF>(m, m));  // row_bcast31 -> rows 2,3
  return m;
}

// ---------------- prep: K = bf16(exp(-||x_i - y_j||^2)), skewed layout ------
// Kpack[(b*511 + kk)*64 + t] : uint2 = 4 bf16 for cells r=0..3
//   cell (i0 = 4t+r, j0 = kk - i0), 0 if j0 out of [0,255]
__global__ __launch_bounds__(256) void softdtw_prep(
    const float* __restrict__ x, const float* __restrict__ y,
    uint2* __restrict__ Kpack)
{
  const int b  = blockIdx.x >> 3;
  const int K0 = (blockIdx.x & 7) << 6;
  const int i0 = threadIdx.x;   // 0..255

  __shared__ __align__(8) unsigned short tileK[64][256];   // [kkL][i0]

  const float* xb = x + ((size_t)b * 256 + i0) * 8;
  float4 xa = *(const float4*)(xb);
  float4 xc = *(const float4*)(xb + 4);
  const float* yb = y + (size_t)b * 256 * 8;

  for (int jj = 0; jj < 64; ++jj) {
    int j0 = K0 + jj - i0;
    bool valid = (unsigned)j0 < 256u;
    int jc = j0 < 0 ? 0 : (j0 > 255 ? 255 : j0);
    const float4* yp = (const float4*)(yb + jc * 8);
    float4 ya = yp[0], yc = yp[1];
    float d, D;
    d = xa.x - ya.x; D = d * d;
    d = xa.y - ya.y; D = fmaf(d, d, D);
    d = xa.z - ya.z; D = fmaf(d, d, D);
    d = xa.w - ya.w; D = fmaf(d, d, D);
    d = xc.x - yc.x; D = fmaf(d, d, D);
    d = xc.y - yc.y; D = fmaf(d, d, D);
    d = xc.z - yc.z; D = fmaf(d, d, D);
    d = xc.w - yc.w; D = fmaf(d, d, D);
    float K = valid ? exp2f(-L2E * D) : 0.0f;
    unsigned kb = __builtin_bit_cast(unsigned, K);
    unsigned rn = (kb + 0x7FFFu + ((kb >> 16) & 1u)) >> 16;   // RNE to bf16
    tileK[jj][i0] = (unsigned short)rn;
  }
  __syncthreads();

  const size_t obase = (size_t)b * 511 * 64;
  #pragma unroll
  for (int w = 0; w < 16; ++w) {
    int p = threadIdx.x + (w << 8);
    int kkL = p >> 6, tt = p & 63;
    int kk = K0 + kkL;
    if (kk < 511) {
      uint2 v = *(const uint2*)&tileK[kkL][tt * 4];
      Kpack[obase + (size_t)kk * 64 + tt] = v;
    }
  }
}

// ---------------- DP: fp64 common-scale forward recurrence ------------------
// E (fp64) at common scale 2^Csum. Inner: V = K*(dg+up+lf). RENORM once per
// 8-step block: shift both carried diags so the newest's wave-max lands near
// 2^850. Headroom analysis (R6 post-mortem): EN mid-block <= 2^863; EO (older,
// LARGER by up to e^{single-cell D} ~ 2^144 at corners) <= 2^994 < 2^1024 —
// the R6 NaN was EO ldexp-overflow -> inf -> 0*inf at target 2^997.
__global__ __launch_bounds__(64) void softdtw_dp(
    const uint2* __restrict__ Kpack, float* __restrict__ out)
{
  const int b = blockIdx.x;
  const int t = threadIdx.x;

  const char* kptr = (const char*)(Kpack + (size_t)b * 511 * 64) + t * 8;

  uint2 kr[8];
  #pragma unroll
  for (int q = 0; q < 8; ++q) kr[q] = *(const uint2*)(kptr + q * 512);

  double EA[4] = {0.0, 0.0, 0.0, 0.0};
  double EB[4] = {0.0, 0.0, 0.0, 0.0};
  int Csum = 0;

#define DPSTEP(q, E2, E1, FIRST, PF) do {                                     \
    uint2 kb_ = kr[q];                                                        \
    if (PF) kr[q] = *(const uint2*)(kptr + (q) * 512);                        \
    double K0_ = (double)__builtin_bit_cast(float, kb_.x << 16);              \
    double K1_ = (double)__builtin_bit_cast(float, kb_.x & 0xFFFF0000u);      \
    double K2_ = (double)__builtin_bit_cast(float, kb_.y << 16);              \
    double K3_ = (double)__builtin_bit_cast(float, kb_.y & 0xFFFF0000u);      \
    double dg_ = shup1z_d(E2[3]);                                             \
    double up_ = shup1z_d(E1[3]);                                             \
    if (FIRST) dg_ = (t == 0) ? 1.0 : dg_;                                    \
    double V0_ = K0_ * (dg_   + (up_   + E1[0]));                             \
    double V1_ = K1_ * (E2[0] + (E1[0] + E1[1]));                             \
    double V2_ = K2_ * (E2[1] + (E1[1] + E1[2]));                             \
    double V3_ = K3_ * (E2[2] + (E1[2] + E1[3]));                             \
    E2[0] = V0_; E2[1] = V1_; E2[2] = V2_; E2[3] = V3_;                       \
  } while (0)

  // dead-beat renorm: shift BOTH carried diagonals so wave-max of the newest
  // lands in [2^850, 2^851). hi-word of a positive double bitcast to float
  // preserves ordering (hi stays < 0x7F800000 here, never a NaN-float).
#define RENORM(EN, EO) do {                                                   \
    double m4_ = fmax(fmax(EN[0], EN[1]), fmax(EN[2], EN[3]));                \
    float mh_ = __builtin_bit_cast(float, __double2hiint(m4_));               \
    mh_ = wave_max63(mh_);                                                    \
    int mb_ = __builtin_amdgcn_readlane(__builtin_bit_cast(int, mh_), 63);    \
    int s_ = (mb_ == 0) ? 0 : (1873 - ((mb_ >> 20) & 0x7FF));                 \
    EN[0] = ldexp(EN[0], s_); EN[1] = ldexp(EN[1], s_);                       \
    EN[2] = ldexp(EN[2], s_); EN[3] = ldexp(EN[3], s_);                       \
    EO[0] = ldexp(EO[0], s_); EO[1] = ldexp(EO[1], s_);                       \
    EO[2] = ldexp(EO[2], s_); EO[3] = ldexp(EO[3], s_);                       \
    Csum += s_;                                                               \
  } while (0)

  // 511 steps = 63 blocks of 8 (prefetch + renorm) + tail 7
  kptr += 4096;
  DPSTEP(0, EA, EB, true,  true);
  DPSTEP(1, EB, EA, false, true);
  DPSTEP(2, EA, EB, false, true);
  DPSTEP(3, EB, EA, false, true);
  DPSTEP(4, EA, EB, false, true);
  DPSTEP(5, EB, EA, false, true);
  DPSTEP(6, EA, EB, false, true);
  DPSTEP(7, EB, EA, false, true);
  RENORM(EB, EA);
  for (int blk = 1; blk < 63; ++blk) {
    kptr += 4096;
    DPSTEP(0, EA, EB, false, true);
    DPSTEP(1, EB, EA, false, true);
    DPSTEP(2, EA, EB, false, true);
    DPSTEP(3, EB, EA, false, true);
    DPSTEP(4, EA, EB, false, true);
    DPSTEP(5, EB, EA, false, true);
    DPSTEP(6, EA, EB, false, true);
    DPSTEP(7, EB, EA, false, true);
    RENORM(EB, EA);
  }
  DPSTEP(0, EA, EB, false, false);
  DPSTEP(1, EB, EA, false, false);
  DPSTEP(2, EA, EB, false, false);
  DPSTEP(3, EB, EA, false, false);
  DPSTEP(4, EA, EB, false, false);
  DPSTEP(5, EB, EA, false, false);
  DPSTEP(6, EA, EB, false, false);   // step 510 -> EA, result in EA[3]@lane63

  if (t == 63) {
    // true E = stored * 2^-Csum ; out = ln2 * (Csum - log2(stored))
    int ex;
    double mant = frexp(EA[3], &ex);   // mant in [0.5, 1)
    float l2 = (float)ex + flog2((float)mant);
    out[b] = (float)(LN2 * ((double)Csum - (double)l2));
  }
}

// ---------------- fallback (R1 log-domain kernel), used if ws too small -----
#if __has_builtin(__builtin_amdgcn_exp2f)
__device__ __forceinline__ float fexp2(float x) { return __builtin_amdgcn_exp2f(x); }
#else
__device__ __forceinline__ float fexp2(float x) { return exp2f(x); }
#endif

__global__ __launch_bounds__(64) void softdtw_fallback(
    const float* __restrict__ x, const float* __restrict__ y,
    float* __restrict__ out)
{
  const int b = blockIdx.x;
  const int t = threadIdx.x;
  __shared__ float zbuf[4][64][9];
  const float* xb = x + (size_t)b * 256 * 8;
  const float* yb = y + (size_t)b * 256 * 8;
  float xe[4][9];
  float x2L[4];
  #pragma unroll
  for (int r = 0; r < 4; ++r) {
    const int row = 4 * t + r;
    float4 a = *(const float4*)(yb + row * 8);
    float4 c = *(const float4*)(yb + row * 8 + 4);
    float y2 = a.x*a.x + a.y*a.y + a.z*a.z + a.w*a.w
             + c.x*c.x + c.y*c.y + c.z*c.z + c.w*c.w;
    float* zr = &zbuf[r][t][0];
    zr[0] = -2.0f*L2E*a.x; zr[1] = -2.0f*L2E*a.y; zr[2] = -2.0f*L2E*a.z; zr[3] = -2.0f*L2E*a.w;
    zr[4] = -2.0f*L2E*c.x; zr[5] = -2.0f*L2E*c.y; zr[6] = -2.0f*L2E*c.z; zr[7] = -2.0f*L2E*c.w;
    zr[8] = L2E * y2;
    float4 xa = *(const float4*)(xb + row * 8);
    float4 xc = *(const float4*)(xb + row * 8 + 4);
    xe[r][0]=xa.x; xe[r][1]=xa.y; xe[r][2]=xa.z; xe[r][3]=xa.w;
    xe[r][4]=xc.x; xe[r][5]=xc.y; xe[r][6]=xc.z; xe[r][7]=xc.w; xe[r][8]=1.0f;
    x2L[r] = L2E*(xa.x*xa.x + xa.y*xa.y + xa.z*xa.z + xa.w*xa.w
                + xc.x*xc.x + xc.y*xc.y + xc.z*xc.z + xc.w*xc.w);
  }
  __syncthreads();
  float zA[9], zB[9], zC[9], zD[9];
  #pragma unroll
  for (int w = 0; w < 9; ++w) { zA[w]=0.f; zB[w]=0.f; zC[w]=0.f; zD[w]=0.f; }
  float RA[4] = {BIGL,BIGL,BIGL,BIGL};
  float RB[4] = {BIGL,BIGL,BIGL,BIGL};
  int u = -4 * t;
  auto ROW = [&](int r, float a, float bb, float c, const float (&zr)[9]) -> float {
    float acc = x2L[r];
    #pragma unroll
    for (int d = 0; d < 9; ++d) acc = fmaf(xe[r][d], zr[d], acc);
    float m = fminf(fminf(a, bb), c);
    float e = fexp2(m-a) + fexp2(m-bb) + fexp2(m-c);
    float val = acc + (m - flog2(e));
    return ((unsigned)(u - r) < 256u) ? val : BIGL;
  };
  auto STEP = [&](float (&zw)[9], const float (&zx)[9], const float (&zy)[9],
                  const float (&zz)[9], float (&Rm2)[4], float (&Rm1)[4],
                  int p, int k) {
    int uc = u < 0 ? 0 : (u > 255 ? 255 : u);
    const float* zp = &zbuf[p][uc >> 2][0];
    #pragma unroll
    for (int w = 0; w < 9; ++w) zw[w] = zp[w];
    float up_in = __shfl_up(Rm1[3], 1);
    float dg_in = __shfl_up(Rm2[3], 1);
    float bval = (k == 2) ? 0.0f : BIGL;
    if (t == 0) { up_in = BIGL; dg_in = bval; }
    float n0 = ROW(0, dg_in,  up_in,  Rm1[0], zw);
    float n1 = ROW(1, Rm2[0], Rm1[0], Rm1[1], zx);
    float n2 = ROW(2, Rm2[1], Rm1[1], Rm1[2], zy);
    float n3 = ROW(3, Rm2[2], Rm1[2], Rm1[3], zz);
    Rm2[0]=n0; Rm2[1]=n1; Rm2[2]=n2; Rm2[3]=n3;
    u += 1;
  };
  int k = 2;
  for (int mi = 0; mi < 127; ++mi) {
    STEP(zD, zA, zB, zC, RA, RB, 0, k);
    STEP(zC, zD, zA, zB, RB, RA, 1, k + 1);
    STEP(zB, zC, zD, zA, RA, RB, 2, k + 2);
    STEP(zA, zB, zC, zD, RB, RA, 3, k + 3);
    k += 4;
  }
  STEP(zD, zA, zB, zC, RA, RB, 0, k);
  STEP(zC, zD, zA, zB, RB, RA, 1, k + 1);
  STEP(zB, zC, zD, zA, RA, RB, 2, k + 2);
  if (t == 63) out[b] = RA[3] * LN2;
}

extern "C" void kernel_launch(void* const* d_in, const int* in_sizes, int n_in,
                              void* d_out, int out_size, void* d_ws, size_t ws_size,
                              hipStream_t stream) {
  const float* x = (const float*)d_in[0];
  const float* y = (const float*)d_in[1];
  float* out = (float*)d_out;
  const int B = in_sizes[0] / (256 * 8);
  const size_t need = (size_t)B * 511 * 64 * 8 + 512;  // Kpack + prefetch slack
  if (ws_size >= need) {
    uint2* Kpack = (uint2*)d_ws;
    softdtw_prep<<<dim3(B * 8), dim3(256), 0, stream>>>(x, y, Kpack);
    softdtw_dp<<<dim3(B), dim3(64), 0, stream>>>(Kpack, out);
  } else {
    softdtw_fallback<<<dim3(B), dim3(64), 0, stream>>>(x, y, out);
  }
}

// Round 8
// 61.640 us; speedup vs baseline: 2.0346x; 1.0990x over previous
//
#include <hip/hip_runtime.h>

#ifndef __has_builtin
#define __has_builtin(x) 0
#endif

#if __has_builtin(__builtin_amdgcn_logf)
__device__ __forceinline__ float flog2(float x) { return __builtin_amdgcn_logf(x); }
#else
__device__ __forceinline__ float flog2(float x) { return log2f(x); }
#endif
#if __has_builtin(__builtin_amdgcn_exp2f)
__device__ __forceinline__ float fexp2(float x) { return __builtin_amdgcn_exp2f(x); }
#else
__device__ __forceinline__ float fexp2(float x) { return exp2f(x); }
#endif

#define L2E 1.4426950408889634f   // log2(e)
#define LN2 0.6931471805599453
#define BIGL (1.0e10f * L2E)

template <int CTRL, int RM, int BM>
__device__ __forceinline__ float dpp_f(float v, float old) {
  int r = __builtin_amdgcn_update_dpp(__builtin_bit_cast(int, old),
                                      __builtin_bit_cast(int, v),
                                      CTRL, RM, BM, false);
  return __builtin_bit_cast(float, r);
}

// lane i <- lane i-1; lane 0 <- 0. fp64 via DPP on both halves.
__device__ __forceinline__ double shup1z_d(double v) {
  int lo = __double2loint(v), hi = __double2hiint(v);
  int lo2 = __builtin_amdgcn_update_dpp(0, lo, 0x138, 0xF, 0xF, false);
  int hi2 = __builtin_amdgcn_update_dpp(0, hi, 0x138, 0xF, 0xF, false);
  return __hiloint2double(hi2, lo2);
}

// wave max -> lane 63 (nonnegative floats)
__device__ __forceinline__ float wave_max63(float m) {
  m = fmaxf(m, dpp_f<0x111, 0xF, 0xF>(m, m));  // row_shr:1
  m = fmaxf(m, dpp_f<0x112, 0xF, 0xF>(m, m));  // row_shr:2
  m = fmaxf(m, dpp_f<0x114, 0xF, 0xF>(m, m));  // row_shr:4
  m = fmaxf(m, dpp_f<0x118, 0xF, 0xF>(m, m));  // row_shr:8
  m = fmaxf(m, dpp_f<0x142, 0xA, 0xF>(m, m));  // row_bcast15 -> rows 1,3
  m = fmaxf(m, dpp_f<0x143, 0xC, 0xF>(m, m));  // row_bcast31 -> rows 2,3
  return m;
}

// ---------------- prep: K = bf16(exp(-||x_i - y_j||^2)), skewed layout ------
// GRID TRANSPOSED for XCD alignment: blockIdx = x*B + b, so all 8 tiles of
// batch b are written from XCD (b%8) == the XCD dp block b will run on —
// dp's K reads then hit the local (coherent) L2 instead of a remote XCD's.
__global__ __launch_bounds__(256) void softdtw_prep(
    const float* __restrict__ x, const float* __restrict__ y,
    uint2* __restrict__ Kpack, int B)
{
  const int b  = blockIdx.x % B;
  const int K0 = (blockIdx.x / B) << 6;
  const int i0 = threadIdx.x;   // 0..255

  __shared__ __align__(8) unsigned short tileK[64][256];   // [kkL][i0]

  const float* xb = x + ((size_t)b * 256 + i0) * 8;
  float4 xa = *(const float4*)(xb);
  float4 xc = *(const float4*)(xb + 4);
  const float* yb = y + (size_t)b * 256 * 8;

  for (int jj = 0; jj < 64; ++jj) {
    int j0 = K0 + jj - i0;
    bool valid = (unsigned)j0 < 256u;
    int jc = j0 < 0 ? 0 : (j0 > 255 ? 255 : j0);
    const float4* yp = (const float4*)(yb + jc * 8);
    float4 ya = yp[0], yc = yp[1];
    float d, D;
    d = xa.x - ya.x; D = d * d;
    d = xa.y - ya.y; D = fmaf(d, d, D);
    d = xa.z - ya.z; D = fmaf(d, d, D);
    d = xa.w - ya.w; D = fmaf(d, d, D);
    d = xc.x - yc.x; D = fmaf(d, d, D);
    d = xc.y - yc.y; D = fmaf(d, d, D);
    d = xc.z - yc.z; D = fmaf(d, d, D);
    d = xc.w - yc.w; D = fmaf(d, d, D);
    float K = valid ? fexp2(-L2E * D) : 0.0f;
    unsigned kb = __builtin_bit_cast(unsigned, K);
    unsigned rn = (kb + 0x7FFFu + ((kb >> 16) & 1u)) >> 16;   // RNE to bf16
    tileK[jj][i0] = (unsigned short)rn;
  }
  __syncthreads();

  const size_t obase = (size_t)b * 511 * 64;
  #pragma unroll
  for (int w = 0; w < 16; ++w) {
    int p = threadIdx.x + (w << 8);
    int kkL = p >> 6, tt = p & 63;
    int kk = K0 + kkL;
    if (kk < 511) {
      uint2 v = *(const uint2*)&tileK[kkL][tt * 4];
      Kpack[obase + (size_t)kk * 64 + tt] = v;
    }
  }
}

// ---------------- DP: fp64 common-scale forward recurrence ------------------
// E (fp64) at common scale 2^Csum. Inner: V = K*(dg+up+lf). RENORM per 8-step
// block, target 2^850 (R6 headroom analysis). dg-carry: dg(k) == up(k-1), so
// only 2 DPP ops/step; the carried value must be rescaled in RENORM too.
__global__ __launch_bounds__(64) void softdtw_dp(
    const uint2* __restrict__ Kpack, float* __restrict__ out)
{
  const int b = blockIdx.x;
  const int t = threadIdx.x;

  const char* kptr = (const char*)(Kpack + (size_t)b * 511 * 64) + t * 8;

  uint2 kr[8];
  #pragma unroll
  for (int q = 0; q < 8; ++q) kr[q] = *(const uint2*)(kptr + q * 512);

  double EA[4] = {0.0, 0.0, 0.0, 0.0};
  double EB[4] = {0.0, 0.0, 0.0, 0.0};
  double dgc = 0.0;          // carried: shup(diag k-2 [3]) for the next step
  int Csum = 0;

#define DPSTEP(q, E2, E1, FIRST, PF) do {                                     \
    uint2 kb_ = kr[q];                                                        \
    if (PF) kr[q] = *(const uint2*)(kptr + (q) * 512);                        \
    double K0_ = (double)__builtin_bit_cast(float, kb_.x << 16);              \
    double K1_ = (double)__builtin_bit_cast(float, kb_.x & 0xFFFF0000u);      \
    double K2_ = (double)__builtin_bit_cast(float, kb_.y << 16);              \
    double K3_ = (double)__builtin_bit_cast(float, kb_.y & 0xFFFF0000u);      \
    double up_ = shup1z_d(E1[3]);                                             \
    double dg_ = dgc;                                                         \
    if (FIRST) dg_ = (t == 0) ? 1.0 : dg_;                                    \
    double V0_ = K0_ * (dg_   + (up_   + E1[0]));                             \
    double V1_ = K1_ * (E2[0] + (E1[0] + E1[1]));                             \
    double V2_ = K2_ * (E2[1] + (E1[1] + E1[2]));                             \
    double V3_ = K3_ * (E2[2] + (E1[2] + E1[3]));                             \
    dgc = up_;                                                                \
    E2[0] = V0_; E2[1] = V1_; E2[2] = V2_; E2[3] = V3_;                       \
  } while (0)

#define RENORM(EN, EO) do {                                                   \
    double m4_ = fmax(fmax(EN[0], EN[1]), fmax(EN[2], EN[3]));                \
    float mh_ = __builtin_bit_cast(float, __double2hiint(m4_));               \
    mh_ = wave_max63(mh_);                                                    \
    int mb_ = __builtin_amdgcn_readlane(__builtin_bit_cast(int, mh_), 63);    \
    int s_ = (mb_ == 0) ? 0 : (1873 - ((mb_ >> 20) & 0x7FF));                 \
    EN[0] = ldexp(EN[0], s_); EN[1] = ldexp(EN[1], s_);                       \
    EN[2] = ldexp(EN[2], s_); EN[3] = ldexp(EN[3], s_);                       \
    EO[0] = ldexp(EO[0], s_); EO[1] = ldexp(EO[1], s_);                       \
    EO[2] = ldexp(EO[2], s_); EO[3] = ldexp(EO[3], s_);                       \
    dgc = ldexp(dgc, s_);                                                     \
    Csum += s_;                                                               \
  } while (0)

  // 511 steps = 63 blocks of 8 (prefetch + renorm) + tail 7
  kptr += 4096;
  DPSTEP(0, EA, EB, true,  true);
  DPSTEP(1, EB, EA, false, true);
  DPSTEP(2, EA, EB, false, true);
  DPSTEP(3, EB, EA, false, true);
  DPSTEP(4, EA, EB, false, true);
  DPSTEP(5, EB, EA, false, true);
  DPSTEP(6, EA, EB, false, true);
  DPSTEP(7, EB, EA, false, true);
  RENORM(EB, EA);
  for (int blk = 1; blk < 63; ++blk) {
    kptr += 4096;
    DPSTEP(0, EA, EB, false, true);
    DPSTEP(1, EB, EA, false, true);
    DPSTEP(2, EA, EB, false, true);
    DPSTEP(3, EB, EA, false, true);
    DPSTEP(4, EA, EB, false, true);
    DPSTEP(5, EB, EA, false, true);
    DPSTEP(6, EA, EB, false, true);
    DPSTEP(7, EB, EA, false, true);
    RENORM(EB, EA);
  }
  DPSTEP(0, EA, EB, false, false);
  DPSTEP(1, EB, EA, false, false);
  DPSTEP(2, EA, EB, false, false);
  DPSTEP(3, EB, EA, false, false);
  DPSTEP(4, EA, EB, false, false);
  DPSTEP(5, EB, EA, false, false);
  DPSTEP(6, EA, EB, false, false);   // step 510 -> EA, result in EA[3]@lane63

  if (t == 63) {
    int ex;
    double mant = frexp(EA[3], &ex);   // mant in [0.5, 1)
    float l2 = (float)ex + flog2((float)mant);
    out[b] = (float)(LN2 * ((double)Csum - (double)l2));
  }
}

// ---------------- fallback (R1 log-domain kernel), used if ws too small -----
__global__ __launch_bounds__(64) void softdtw_fallback(
    const float* __restrict__ x, const float* __restrict__ y,
    float* __restrict__ out)
{
  const int b = blockIdx.x;
  const int t = threadIdx.x;
  __shared__ float zbuf[4][64][9];
  const float* xb = x + (size_t)b * 256 * 8;
  const float* yb = y + (size_t)b * 256 * 8;
  float xe[4][9];
  float x2L[4];
  #pragma unroll
  for (int r = 0; r < 4; ++r) {
    const int row = 4 * t + r;
    float4 a = *(const float4*)(yb + row * 8);
    float4 c = *(const float4*)(yb + row * 8 + 4);
    float y2 = a.x*a.x + a.y*a.y + a.z*a.z + a.w*a.w
             + c.x*c.x + c.y*c.y + c.z*c.z + c.w*c.w;
    float* zr = &zbuf[r][t][0];
    zr[0] = -2.0f*L2E*a.x; zr[1] = -2.0f*L2E*a.y; zr[2] = -2.0f*L2E*a.z; zr[3] = -2.0f*L2E*a.w;
    zr[4] = -2.0f*L2E*c.x; zr[5] = -2.0f*L2E*c.y; zr[6] = -2.0f*L2E*c.z; zr[7] = -2.0f*L2E*c.w;
    zr[8] = L2E * y2;
    float4 xa = *(const float4*)(xb + row * 8);
    float4 xc = *(const float4*)(xb + row * 8 + 4);
    xe[r][0]=xa.x; xe[r][1]=xa.y; xe[r][2]=xa.z; xe[r][3]=xa.w;
    xe[r][4]=xc.x; xe[r][5]=xc.y; xe[r][6]=xc.z; xe[r][7]=xc.w; xe[r][8]=1.0f;
    x2L[r] = L2E*(xa.x*xa.x + xa.y*xa.y + xa.z*xa.z + xa.w*xa.w
                + xc.x*xc.x + xc.y*xc.y + xc.z*xc.z + xc.w*xc.w);
  }
  __syncthreads();
  float zA[9], zB[9], zC[9], zD[9];
  #pragma unroll
  for (int w = 0; w < 9; ++w) { zA[w]=0.f; zB[w]=0.f; zC[w]=0.f; zD[w]=0.f; }
  float RA[4] = {BIGL,BIGL,BIGL,BIGL};
  float RB[4] = {BIGL,BIGL,BIGL,BIGL};
  int u = -4 * t;
  auto ROW = [&](int r, float a, float bb, float c, const float (&zr)[9]) -> float {
    float acc = x2L[r];
    #pragma unroll
    for (int d = 0; d < 9; ++d) acc = fmaf(xe[r][d], zr[d], acc);
    float m = fminf(fminf(a, bb), c);
    float e = fexp2(m-a) + fexp2(m-bb) + fexp2(m-c);
    float val = acc + (m - flog2(e));
    return ((unsigned)(u - r) < 256u) ? val : BIGL;
  };
  auto STEP = [&](float (&zw)[9], const float (&zx)[9], const float (&zy)[9],
                  const float (&zz)[9], float (&Rm2)[4], float (&Rm1)[4],
                  int p, int k) {
    int uc = u < 0 ? 0 : (u > 255 ? 255 : u);
    const float* zp = &zbuf[p][uc >> 2][0];
    #pragma unroll
    for (int w = 0; w < 9; ++w) zw[w] = zp[w];
    float up_in = __shfl_up(Rm1[3], 1);
    float dg_in = __shfl_up(Rm2[3], 1);
    float bval = (k == 2) ? 0.0f : BIGL;
    if (t == 0) { up_in = BIGL; dg_in = bval; }
    float n0 = ROW(0, dg_in,  up_in,  Rm1[0], zw);
    float n1 = ROW(1, Rm2[0], Rm1[0], Rm1[1], zx);
    float n2 = ROW(2, Rm2[1], Rm1[1], Rm1[2], zy);
    float n3 = ROW(3, Rm2[2], Rm1[2], Rm1[3], zz);
    Rm2[0]=n0; Rm2[1]=n1; Rm2[2]=n2; Rm2[3]=n3;
    u += 1;
  };
  int k = 2;
  for (int mi = 0; mi < 127; ++mi) {
    STEP(zD, zA, zB, zC, RA, RB, 0, k);
    STEP(zC, zD, zA, zB, RB, RA, 1, k + 1);
    STEP(zB, zC, zD, zA, RA, RB, 2, k + 2);
    STEP(zA, zB, zC, zD, RB, RA, 3, k + 3);
    k += 4;
  }
  STEP(zD, zA, zB, zC, RA, RB, 0, k);
  STEP(zC, zD, zA, zB, RB, RA, 1, k + 1);
  STEP(zB, zC, zD, zA, RA, RB, 2, k + 2);
  if (t == 63) out[b] = RA[3] * LN2;
}

extern "C" void kernel_launch(void* const* d_in, const int* in_sizes, int n_in,
                              void* d_out, int out_size, void* d_ws, size_t ws_size,
                              hipStream_t stream) {
  const float* x = (const float*)d_in[0];
  const float* y = (const float*)d_in[1];
  float* out = (float*)d_out;
  const int B = in_sizes[0] / (256 * 8);
  const size_t need = (size_t)B * 511 * 64 * 8 + 512;  // Kpack + prefetch slack
  if (ws_size >= need) {
    uint2* Kpack = (uint2*)d_ws;
    softdtw_prep<<<dim3(B * 8), dim3(256), 0, stream>>>(x, y, Kpack, B);
    softdtw_dp<<<dim3(B), dim3(64), 0, stream>>>(Kpack, out);
  } else {
    softdtw_fallback<<<dim3(B), dim3(64), 0, stream>>>(x, y, out);
  }
}

// Round 9
// 55.845 us; speedup vs baseline: 2.2457x; 1.1038x over previous
//
#include <hip/hip_runtime.h>

#ifndef __has_builtin
#define __has_builtin(x) 0
#endif

#if __has_builtin(__builtin_amdgcn_logf)
__device__ __forceinline__ float flog2(float x) { return __builtin_amdgcn_logf(x); }
#else
__device__ __forceinline__ float flog2(float x) { return log2f(x); }
#endif
#if __has_builtin(__builtin_amdgcn_exp2f)
__device__ __forceinline__ float fexp2(float x) { return __builtin_amdgcn_exp2f(x); }
#else
__device__ __forceinline__ float fexp2(float x) { return exp2f(x); }
#endif

#define L2E 1.4426950408889634f   // log2(e)
#define LN2 0.6931471805599453
#define BIGL (1.0e10f * L2E)

template <int CTRL, int RM, int BM>
__device__ __forceinline__ float dpp_f(float v, float old) {
  int r = __builtin_amdgcn_update_dpp(__builtin_bit_cast(int, old),
                                      __builtin_bit_cast(int, v),
                                      CTRL, RM, BM, false);
  return __builtin_bit_cast(float, r);
}

// lane i <- lane i-1; lane 0 <- 0. fp64 via DPP on both halves.
__device__ __forceinline__ double shup1z_d(double v) {
  int lo = __double2loint(v), hi = __double2hiint(v);
  int lo2 = __builtin_amdgcn_update_dpp(0, lo, 0x138, 0xF, 0xF, false);
  int hi2 = __builtin_amdgcn_update_dpp(0, hi, 0x138, 0xF, 0xF, false);
  return __hiloint2double(hi2, lo2);
}

// wave max -> lane 63 (nonnegative floats)
__device__ __forceinline__ float wave_max63(float m) {
  m = fmaxf(m, dpp_f<0x111, 0xF, 0xF>(m, m));  // row_shr:1
  m = fmaxf(m, dpp_f<0x112, 0xF, 0xF>(m, m));  // row_shr:2
  m = fmaxf(m, dpp_f<0x114, 0xF, 0xF>(m, m));  // row_shr:4
  m = fmaxf(m, dpp_f<0x118, 0xF, 0xF>(m, m));  // row_shr:8
  m = fmaxf(m, dpp_f<0x142, 0xA, 0xF>(m, m));  // row_bcast15 -> rows 1,3
  m = fmaxf(m, dpp_f<0x143, 0xC, 0xF>(m, m));  // row_bcast31 -> rows 2,3
  return m;
}

// ---------------- prep: K = bf16(exp(-||x_i - y_j||^2)), PAIR-major layout --
// Kpack as uint4: Kp4[b*16384 + kk2*64 + tt] = 16B holding lane tt's cells for
// diag pair {2*kk2, 2*kk2+1} (xy = even diag, zw = odd diag). This makes the
// dp kernel's 16-step chunk a contiguous-stride dwordx4 stream (8 loads/chunk).
// Diag slot 511 is covered by tileK row 63 of the last block == all zeros
// (valid-mask), so the pair-31 hi half is clean zero, never fake mass.
__global__ __launch_bounds__(256) void softdtw_prep(
    const float* __restrict__ x, const float* __restrict__ y,
    uint4* __restrict__ Kp4, int B)
{
  const int b  = blockIdx.x % B;            // XCD-aligned with dp block b
  const int K0 = (blockIdx.x / B) << 6;
  const int i0 = threadIdx.x;               // 0..255

  __shared__ __align__(16) unsigned short tileK[64][256];   // [kkL][i0]

  const float* xb = x + ((size_t)b * 256 + i0) * 8;
  float4 xa = *(const float4*)(xb);
  float4 xc = *(const float4*)(xb + 4);
  const float* yb = y + (size_t)b * 256 * 8;

  for (int jj = 0; jj < 64; ++jj) {
    int j0 = K0 + jj - i0;
    bool valid = (unsigned)j0 < 256u;
    int jc = j0 < 0 ? 0 : (j0 > 255 ? 255 : j0);
    const float4* yp = (const float4*)(yb + jc * 8);
    float4 ya = yp[0], yc = yp[1];
    float d, D;
    d = xa.x - ya.x; D = d * d;
    d = xa.y - ya.y; D = fmaf(d, d, D);
    d = xa.z - ya.z; D = fmaf(d, d, D);
    d = xa.w - ya.w; D = fmaf(d, d, D);
    d = xc.x - yc.x; D = fmaf(d, d, D);
    d = xc.y - yc.y; D = fmaf(d, d, D);
    d = xc.z - yc.z; D = fmaf(d, d, D);
    d = xc.w - yc.w; D = fmaf(d, d, D);
    float K = valid ? fexp2(-L2E * D) : 0.0f;
    unsigned kb = __builtin_bit_cast(unsigned, K);
    unsigned rn = (kb + 0x7FFFu + ((kb >> 16) & 1u)) >> 16;   // RNE to bf16
    tileK[jj][i0] = (unsigned short)rn;
  }
  __syncthreads();

  // fully-coalesced uint4 transpose-store: 32 diag-pairs x 64 lanes per block
  const size_t obase4 = (size_t)b * 16384;   // uint4 units per batch
  #pragma unroll
  for (int w = 0; w < 8; ++w) {
    int p = threadIdx.x + (w << 8);          // 0..2047
    int kkP = p >> 6;                        // local pair 0..31
    int tt = p & 63;
    uint2 lo = *(const uint2*)&tileK[kkP * 2][tt * 4];
    uint2 hi = *(const uint2*)&tileK[kkP * 2 + 1][tt * 4];
    uint4 v; v.x = lo.x; v.y = lo.y; v.z = hi.x; v.w = hi.y;
    Kp4[obase4 + (size_t)((K0 >> 1) + kkP) * 64 + tt] = v;
  }
}

// ---------------- DP: fp64 common-scale forward recurrence ------------------
// E (fp64) at common scale 2^Csum. Inner: V = K*(dg+up+lf). RENORM per 8 steps
// (target 2^800; EO headroom >= 2^95). K stream consumed in 16-step chunks,
// DOUBLE-BUFFERED: 8 x dwordx4 issued at chunk top (sched_barrier-pinned),
// consumed one chunk later -> ~1300 cyc slack, no per-step waitcnt stall.
__global__ __launch_bounds__(64) void softdtw_dp(
    const uint4* __restrict__ Kp4, float* __restrict__ out)
{
  const int b = blockIdx.x;
  const int t = threadIdx.x;

  const char* kbase = (const char*)(Kp4 + (size_t)b * 16384) + t * 16;

  double EA[4] = {0.0, 0.0, 0.0, 0.0};
  double EB[4] = {0.0, 0.0, 0.0, 0.0};
  double dgc = 0.0;          // carried: shup(diag s-2 [3]) for the next step
  int Csum = 0;

#define DPSTEP2(KAw, KBw, E2, E1, FIRSTF) do {                                \
    double K0_ = (double)__builtin_bit_cast(float, (KAw) << 16);              \
    double K1_ = (double)__builtin_bit_cast(float, (KAw) & 0xFFFF0000u);      \
    double K2_ = (double)__builtin_bit_cast(float, (KBw) << 16);              \
    double K3_ = (double)__builtin_bit_cast(float, (KBw) & 0xFFFF0000u);      \
    double up_ = shup1z_d(E1[3]);                                             \
    double dg_ = dgc;                                                         \
    if (FIRSTF) dg_ = (t == 0) ? 1.0 : dg_;                                   \
    double V0_ = K0_ * (dg_   + (up_   + E1[0]));                             \
    double V1_ = K1_ * (E2[0] + (E1[0] + E1[1]));                             \
    double V2_ = K2_ * (E2[1] + (E1[1] + E1[2]));                             \
    double V3_ = K3_ * (E2[2] + (E1[2] + E1[3]));                             \
    dgc = up_;                                                                \
    E2[0] = V0_; E2[1] = V1_; E2[2] = V2_; E2[3] = V3_;                       \
  } while (0)

#define RENORM(EN, EO) do {                                                   \
    double m4_ = fmax(fmax(EN[0], EN[1]), fmax(EN[2], EN[3]));                \
    float mh_ = __builtin_bit_cast(float, __double2hiint(m4_));               \
    mh_ = wave_max63(mh_);                                                    \
    int mb_ = __builtin_amdgcn_readlane(__builtin_bit_cast(int, mh_), 63);    \
    int s_ = (mb_ == 0) ? 0 : (1823 - ((mb_ >> 20) & 0x7FF));                 \
    EN[0] = ldexp(EN[0], s_); EN[1] = ldexp(EN[1], s_);                       \
    EN[2] = ldexp(EN[2], s_); EN[3] = ldexp(EN[3], s_);                       \
    EO[0] = ldexp(EO[0], s_); EO[1] = ldexp(EO[1], s_);                       \
    EO[2] = ldexp(EO[2], s_); EO[3] = ldexp(EO[3], s_);                       \
    dgc = ldexp(dgc, s_);                                                     \
    Csum += s_;                                                               \
  } while (0)

  // one 16-step chunk: issue next chunk's 8 loads into LB, compute from CB
#define CHUNK16(CB, LB, FIRSTF) do {                                          \
    LB[0] = *(const uint4*)(kbase);                                           \
    LB[1] = *(const uint4*)(kbase + 1024);                                    \
    LB[2] = *(const uint4*)(kbase + 2048);                                    \
    LB[3] = *(const uint4*)(kbase + 3072);                                    \
    LB[4] = *(const uint4*)(kbase + 4096);                                    \
    LB[5] = *(const uint4*)(kbase + 5120);                                    \
    LB[6] = *(const uint4*)(kbase + 6144);                                    \
    LB[7] = *(const uint4*)(kbase + 7168);                                    \
    kbase += 8192;                                                            \
    __builtin_amdgcn_sched_barrier(0);                                        \
    DPSTEP2(CB[0].x, CB[0].y, EA, EB, FIRSTF);                                \
    DPSTEP2(CB[0].z, CB[0].w, EB, EA, false);                                 \
    DPSTEP2(CB[1].x, CB[1].y, EA, EB, false);                                 \
    DPSTEP2(CB[1].z, CB[1].w, EB, EA, false);                                 \
    DPSTEP2(CB[2].x, CB[2].y, EA, EB, false);                                 \
    DPSTEP2(CB[2].z, CB[2].w, EB, EA, false);                                 \
    DPSTEP2(CB[3].x, CB[3].y, EA, EB, false);                                 \
    DPSTEP2(CB[3].z, CB[3].w, EB, EA, false);                                 \
    RENORM(EB, EA);                                                           \
    DPSTEP2(CB[4].x, CB[4].y, EA, EB, false);                                 \
    DPSTEP2(CB[4].z, CB[4].w, EB, EA, false);                                 \
    DPSTEP2(CB[5].x, CB[5].y, EA, EB, false);                                 \
    DPSTEP2(CB[5].z, CB[5].w, EB, EA, false);                                 \
    DPSTEP2(CB[6].x, CB[6].y, EA, EB, false);                                 \
    DPSTEP2(CB[6].z, CB[6].w, EB, EA, false);                                 \
    DPSTEP2(CB[7].x, CB[7].y, EA, EB, false);                                 \
    DPSTEP2(CB[7].z, CB[7].w, EB, EA, false);                                 \
    RENORM(EB, EA);                                                           \
  } while (0)

  uint4 KA[8], KB[8];
  // preload chunk 0 (pairs 0..7)
  KA[0] = *(const uint4*)(kbase);
  KA[1] = *(const uint4*)(kbase + 1024);
  KA[2] = *(const uint4*)(kbase + 2048);
  KA[3] = *(const uint4*)(kbase + 3072);
  KA[4] = *(const uint4*)(kbase + 4096);
  KA[5] = *(const uint4*)(kbase + 5120);
  KA[6] = *(const uint4*)(kbase + 6144);
  KA[7] = *(const uint4*)(kbase + 7168);
  kbase += 8192;

  CHUNK16(KA, KB, true);            // chunk 0 (steps 0..15), loads chunk 1
  #pragma unroll 1
  for (int c = 0; c < 15; ++c) {    // chunks 1..30 (steps 16..495)
    CHUNK16(KB, KA, false);
    CHUNK16(KA, KB, false);
  }
  // tail: steps 496..510 (15 steps) from KB (pairs 248..255), no loads
  DPSTEP2(KB[0].x, KB[0].y, EA, EB, false);
  DPSTEP2(KB[0].z, KB[0].w, EB, EA, false);
  DPSTEP2(KB[1].x, KB[1].y, EA, EB, false);
  DPSTEP2(KB[1].z, KB[1].w, EB, EA, false);
  DPSTEP2(KB[2].x, KB[2].y, EA, EB, false);
  DPSTEP2(KB[2].z, KB[2].w, EB, EA, false);
  DPSTEP2(KB[3].x, KB[3].y, EA, EB, false);
  DPSTEP2(KB[3].z, KB[3].w, EB, EA, false);
  RENORM(EB, EA);
  DPSTEP2(KB[4].x, KB[4].y, EA, EB, false);
  DPSTEP2(KB[4].z, KB[4].w, EB, EA, false);
  DPSTEP2(KB[5].x, KB[5].y, EA, EB, false);
  DPSTEP2(KB[5].z, KB[5].w, EB, EA, false);
  DPSTEP2(KB[6].x, KB[6].y, EA, EB, false);
  DPSTEP2(KB[6].z, KB[6].w, EB, EA, false);
  DPSTEP2(KB[7].x, KB[7].y, EA, EB, false);   // step 510 -> EA, result EA[3]

  if (t == 63) {
    int ex;
    double mant = frexp(EA[3], &ex);   // mant in [0.5, 1)
    float l2 = (float)ex + flog2((float)mant);
    out[b] = (float)(LN2 * ((double)Csum - (double)l2));
  }
}

// ---------------- fallback (R1 log-domain kernel), used if ws too small -----
__global__ __launch_bounds__(64) void softdtw_fallback(
    const float* __restrict__ x, const float* __restrict__ y,
    float* __restrict__ out)
{
  const int b = blockIdx.x;
  const int t = threadIdx.x;
  __shared__ float zbuf[4][64][9];
  const float* xb = x + (size_t)b * 256 * 8;
  const float* yb = y + (size_t)b * 256 * 8;
  float xe[4][9];
  float x2L[4];
  #pragma unroll
  for (int r = 0; r < 4; ++r) {
    const int row = 4 * t + r;
    float4 a = *(const float4*)(yb + row * 8);
    float4 c = *(const float4*)(yb + row * 8 + 4);
    float y2 = a.x*a.x + a.y*a.y + a.z*a.z + a.w*a.w
             + c.x*c.x + c.y*c.y + c.z*c.z + c.w*c.w;
    float* zr = &zbuf[r][t][0];
    zr[0] = -2.0f*L2E*a.x; zr[1] = -2.0f*L2E*a.y; zr[2] = -2.0f*L2E*a.z; zr[3] = -2.0f*L2E*a.w;
    zr[4] = -2.0f*L2E*c.x; zr[5] = -2.0f*L2E*c.y; zr[6] = -2.0f*L2E*c.z; zr[7] = -2.0f*L2E*c.w;
    zr[8] = L2E * y2;
    float4 xa = *(const float4*)(xb + row * 8);
    float4 xc = *(const float4*)(xb + row * 8 + 4);
    xe[r][0]=xa.x; xe[r][1]=xa.y; xe[r][2]=xa.z; xe[r][3]=xa.w;
    xe[r][4]=xc.x; xe[r][5]=xc.y; xe[r][6]=xc.z; xe[r][7]=xc.w; xe[r][8]=1.0f;
    x2L[r] = L2E*(xa.x*xa.x + xa.y*xa.y + xa.z*xa.z + xa.w*xa.w
                + xc.x*xc.x + xc.y*xc.y + xc.z*xc.z + xc.w*xc.w);
  }
  __syncthreads();
  float zA[9], zB[9], zC[9], zD[9];
  #pragma unroll
  for (int w = 0; w < 9; ++w) { zA[w]=0.f; zB[w]=0.f; zC[w]=0.f; zD[w]=0.f; }
  float RA[4] = {BIGL,BIGL,BIGL,BIGL};
  float RB[4] = {BIGL,BIGL,BIGL,BIGL};
  int u = -4 * t;
  auto ROW = [&](int r, float a, float bb, float c, const float (&zr)[9]) -> float {
    float acc = x2L[r];
    #pragma unroll
    for (int d = 0; d < 9; ++d) acc = fmaf(xe[r][d], zr[d], acc);
    float m = fminf(fminf(a, bb), c);
    float e = fexp2(m-a) + fexp2(m-bb) + fexp2(m-c);
    float val = acc + (m - flog2(e));
    return ((unsigned)(u - r) < 256u) ? val : BIGL;
  };
  auto STEP = [&](float (&zw)[9], const float (&zx)[9], const float (&zy)[9],
                  const float (&zz)[9], float (&Rm2)[4], float (&Rm1)[4],
                  int p, int k) {
    int uc = u < 0 ? 0 : (u > 255 ? 255 : u);
    const float* zp = &zbuf[p][uc >> 2][0];
    #pragma unroll
    for (int w = 0; w < 9; ++w) zw[w] = zp[w];
    float up_in = __shfl_up(Rm1[3], 1);
    float dg_in = __shfl_up(Rm2[3], 1);
    float bval = (k == 2) ? 0.0f : BIGL;
    if (t == 0) { up_in = BIGL; dg_in = bval; }
    float n0 = ROW(0, dg_in,  up_in,  Rm1[0], zw);
    float n1 = ROW(1, Rm2[0], Rm1[0], Rm1[1], zx);
    float n2 = ROW(2, Rm2[1], Rm1[1], Rm1[2], zy);
    float n3 = ROW(3, Rm2[2], Rm1[2], Rm1[3], zz);
    Rm2[0]=n0; Rm2[1]=n1; Rm2[2]=n2; Rm2[3]=n3;
    u += 1;
  };
  int k = 2;
  for (int mi = 0; mi < 127; ++mi) {
    STEP(zD, zA, zB, zC, RA, RB, 0, k);
    STEP(zC, zD, zA, zB, RB, RA, 1, k + 1);
    STEP(zB, zC, zD, zA, RA, RB, 2, k + 2);
    STEP(zA, zB, zC, zD, RB, RA, 3, k + 3);
    k += 4;
  }
  STEP(zD, zA, zB, zC, RA, RB, 0, k);
  STEP(zC, zD, zA, zB, RB, RA, 1, k + 1);
  STEP(zB, zC, zD, zA, RA, RB, 2, k + 2);
  if (t == 63) out[b] = RA[3] * LN2;
}

extern "C" void kernel_launch(void* const* d_in, const int* in_sizes, int n_in,
                              void* d_out, int out_size, void* d_ws, size_t ws_size,
                              hipStream_t stream) {
  const float* x = (const float*)d_in[0];
  const float* y = (const float*)d_in[1];
  float* out = (float*)d_out;
  const int B = in_sizes[0] / (256 * 8);
  const size_t need = (size_t)B * 262144;   // 256 diag-pairs x 64 lanes x 16B
  if (ws_size >= need) {
    uint4* Kp4 = (uint4*)d_ws;
    softdtw_prep<<<dim3(B * 8), dim3(256), 0, stream>>>(x, y, Kp4, B);
    softdtw_dp<<<dim3(B), dim3(64), 0, stream>>>(Kp4, out);
  } else {
    softdtw_fallback<<<dim3(B), dim3(64), 0, stream>>>(x, y, out);
  }
}